// Round 10
// baseline (39.749 us; speedup 1.0000x reference)
//
#include <hip/hip_runtime.h>

// ConvSurface: out[m,f,k] = max_s relu( (point_{m,f,s} - center_{m,f}) . W_k + b_k )
// Lane = kernel k (64 = wave64). One wave per FACE, m-loop over 8 meshes.
// R10: readlane-broadcast design. Per mesh, the wave's 30 face floats
// (27 corners + 3 center) are loaded COALESCED (lane e -> element e) into ONE
// VGPR d_m; all 8 meshes' loads issue up-front as 8 independent VMEM ops
// (compiler emits counted vmcnt waits). Compute broadcasts each element with
// v_readlane_b32 (VALU pipe -> SGPR; no SQC streaming, no DS pipe, no 30-reg
// prefetch buffers the compiler refuses to keep). beta/gamma: one coalesced
// load + 48 one-time readlanes -> 48 resident SGPRs. Every FMA has exactly
// one uniform (SGPR) operand - legal encoding, no v_mov traffic.
// Algebra: alpha+beta+gamma==1 => p.W = a1 + beta*(a2-a1) + gamma*(a3-a1);
// bias/center-dot/relu folded outside the sample max (monotone).

#define NM 8
#define NF 16384
#define NK 64

#define RL(V, I) __int_as_float(__builtin_amdgcn_readlane(__float_as_int(V), (I)))

// one neighbor: corner elements E..E+8 broadcast from DM, samples from SGPR bs/gs
#define NEI(MX, DM, E, S0,S1,S2,S3,S4,S5,S6,S7) do { \
    const float t0_ = RL(DM, (E)+0), t1_ = RL(DM, (E)+1), t2_ = RL(DM, (E)+2); \
    const float t3_ = RL(DM, (E)+3), t4_ = RL(DM, (E)+4), t5_ = RL(DM, (E)+5); \
    const float t6_ = RL(DM, (E)+6), t7_ = RL(DM, (E)+7), t8_ = RL(DM, (E)+8); \
    const float a1_ = t0_*w0 + t1_*w1 + t2_*w2; \
    const float a2_ = t3_*w0 + t4_*w1 + t5_*w2; \
    const float a3_ = t6_*w0 + t7_*w1 + t8_*w2; \
    const float e2_ = a2_ - a1_, e3_ = a3_ - a1_; \
    const float v0_ = fmaf(bs##S0, e2_, fmaf(gs##S0, e3_, a1_)); \
    const float v1_ = fmaf(bs##S1, e2_, fmaf(gs##S1, e3_, a1_)); \
    const float v2_ = fmaf(bs##S2, e2_, fmaf(gs##S2, e3_, a1_)); \
    const float v3_ = fmaf(bs##S3, e2_, fmaf(gs##S3, e3_, a1_)); \
    const float v4_ = fmaf(bs##S4, e2_, fmaf(gs##S4, e3_, a1_)); \
    const float v5_ = fmaf(bs##S5, e2_, fmaf(gs##S5, e3_, a1_)); \
    const float v6_ = fmaf(bs##S6, e2_, fmaf(gs##S6, e3_, a1_)); \
    const float v7_ = fmaf(bs##S7, e2_, fmaf(gs##S7, e3_, a1_)); \
    const float p0_ = fmaxf(fmaxf(v0_, v1_), v2_); \
    const float p1_ = fmaxf(fmaxf(v3_, v4_), v5_); \
    const float p2_ = fmaxf(fmaxf(v6_, v7_), p0_); \
    MX = fmaxf(MX, fmaxf(p1_, p2_)); \
} while (0)

#define MESH(M, DM) do { \
    const float cx_ = RL(DM, 27), cy_ = RL(DM, 28), cz_ = RL(DM, 29); \
    const float cdot_ = cx_*w0 + cy_*w1 + cz_*w2; \
    float mx_ = -3.4e38f; \
    NEI(mx_, DM, 0,  0,3,6,9,12,15,18,21); \
    NEI(mx_, DM, 9,  1,4,7,10,13,16,19,22); \
    NEI(mx_, DM, 18, 2,5,8,11,14,17,20,23); \
    out[((size_t)(M) * NF + funi) * NK + lane] = fmaxf(mx_ + (bk - cdot_), 0.0f); \
} while (0)

__global__ __launch_bounds__(256, 4) void conv_surface_kernel(
    const float* __restrict__ centers,   // [M,F,3]
    const float* __restrict__ nc,        // [M,F,3,3,3]
    const float* __restrict__ beta,      // [F,24]
    const float* __restrict__ gammav,    // [F,24]
    const float* __restrict__ W,         // [64,3]
    const float* __restrict__ b,         // [64]
    float* __restrict__ out)             // [M,F,64]
{
    const int tid  = threadIdx.x;
    const int lane = tid & 63;
    const int funi = __builtin_amdgcn_readfirstlane(blockIdx.x * 4 + (tid >> 6));

    // per-lane kernel weights (VMEM, L1-resident)
    const float w0 = W[lane * 3 + 0];
    const float w1 = W[lane * 3 + 1];
    const float w2 = W[lane * 3 + 2];
    const float bk = b[lane];

    // beta/gamma: ONE coalesced load (lane<24 -> beta, 24..47 -> gamma),
    // then 48 one-time readlanes -> resident uniform (SGPR) values.
    const int lb = (lane < 48) ? lane : 0;
    const float bgv = (lb < 24)
        ? beta  [(size_t)funi * 24 + lb]
        : gammav[(size_t)funi * 24 + (lb - 24)];
    const float bs0 =RL(bgv, 0), bs1 =RL(bgv, 1), bs2 =RL(bgv, 2), bs3 =RL(bgv, 3);
    const float bs4 =RL(bgv, 4), bs5 =RL(bgv, 5), bs6 =RL(bgv, 6), bs7 =RL(bgv, 7);
    const float bs8 =RL(bgv, 8), bs9 =RL(bgv, 9), bs10=RL(bgv,10), bs11=RL(bgv,11);
    const float bs12=RL(bgv,12), bs13=RL(bgv,13), bs14=RL(bgv,14), bs15=RL(bgv,15);
    const float bs16=RL(bgv,16), bs17=RL(bgv,17), bs18=RL(bgv,18), bs19=RL(bgv,19);
    const float bs20=RL(bgv,20), bs21=RL(bgv,21), bs22=RL(bgv,22), bs23=RL(bgv,23);
    const float gs0 =RL(bgv,24), gs1 =RL(bgv,25), gs2 =RL(bgv,26), gs3 =RL(bgv,27);
    const float gs4 =RL(bgv,28), gs5 =RL(bgv,29), gs6 =RL(bgv,30), gs7 =RL(bgv,31);
    const float gs8 =RL(bgv,32), gs9 =RL(bgv,33), gs10=RL(bgv,34), gs11=RL(bgv,35);
    const float gs12=RL(bgv,36), gs13=RL(bgv,37), gs14=RL(bgv,38), gs15=RL(bgv,39);
    const float gs16=RL(bgv,40), gs17=RL(bgv,41), gs18=RL(bgv,42), gs19=RL(bgv,43);
    const float gs20=RL(bgv,44), gs21=RL(bgv,45), gs22=RL(bgv,46), gs23=RL(bgv,47);

    // face data: lane e holds element e (27 corners | 3 center), one VGPR per
    // mesh, all 8 loads independent and issued up-front (counted vmcnt).
    const int ll = (lane < 30) ? lane : 0;            // lanes 30-63 dup lane 0
    const float* __restrict__ ga = (ll < 27)
        ? (nc      + (size_t)funi * 27 + ll)
        : (centers + (size_t)funi * 3  + (ll - 27));
    const size_t st = (ll < 27) ? (size_t)NF * 27 : (size_t)NF * 3;
    const float d0 = ga[0];
    const float d1 = ga[st];
    const float d2 = ga[2 * st];
    const float d3 = ga[3 * st];
    const float d4 = ga[4 * st];
    const float d5 = ga[5 * st];
    const float d6 = ga[6 * st];
    const float d7 = ga[7 * st];

    MESH(0, d0);
    MESH(1, d1);
    MESH(2, d2);
    MESH(3, d3);
    MESH(4, d4);
    MESH(5, d5);
    MESH(6, d6);
    MESH(7, d7);
}

extern "C" void kernel_launch(void* const* d_in, const int* in_sizes, int n_in,
                              void* d_out, int out_size, void* d_ws, size_t ws_size,
                              hipStream_t stream) {
    const float* centers = (const float*)d_in[0];
    // d_in[1] = ring_n  (unused by the reference math)
    const float* nc      = (const float*)d_in[2];
    // d_in[3] = alpha   (unused: alpha = 1 - beta - gamma)
    const float* beta    = (const float*)d_in[4];
    const float* gammav  = (const float*)d_in[5];
    const float* W       = (const float*)d_in[6];
    const float* b       = (const float*)d_in[7];
    float* out = (float*)d_out;

    dim3 grid(NF / 4), block(256);   // one wave per face, 8 meshes per wave
    hipLaunchKernelGGL(conv_surface_kernel, grid, block, 0, stream,
                       centers, nc, beta, gammav, W, b, out);
}